// Round 1
// 863.807 us; speedup vs baseline: 1.0465x; 1.0465x over previous
//
#include <hip/hip_runtime.h>

// B=64, C=256, L=4096. Tokens b-major: t = b*4096 + l.
// ws: Xt bf16[262144][256] @0 (128MB); Virt bf16[262144][256] @128MB (128MB);
//     Wtv bf16[512][256] @256MB; Wout2 bf16[256][512]; stats fp32[4224]
//     stats: [32][128] partial (sum,b | sumsq,b) then mean[64]@4096, rstd[64]@4160

typedef __attribute__((ext_vector_type(8))) short          v8s;   // 8 x bf16 bits
typedef __attribute__((ext_vector_type(8))) unsigned short v8u;
typedef __attribute__((ext_vector_type(4))) unsigned short v4u;
typedef __attribute__((ext_vector_type(4))) float          f32x4;

#define MFMA16(a, b, c) __builtin_amdgcn_mfma_f32_16x16x32_bf16((a), (b), (c), 0, 0, 0)

static __device__ __forceinline__ unsigned short f2bf(float f) {
  union { float f; unsigned u; } v; v.f = f;
  unsigned r = (v.u + 0x7FFFu + ((v.u >> 16) & 1u)) >> 16;  // RNE
  return (unsigned short)r;
}
static __device__ __forceinline__ float bf2f(unsigned short h) {
  union { unsigned u; float f; } v; v.u = ((unsigned)h) << 16; return v.f;
}

// ---------------- prep: M = Wq^T Wk / 16, W2 = Wout*Wc, bf16 packs, zero stats
__global__ void k_prep(const float* __restrict__ Wq, const float* __restrict__ Wk,
                       const float* __restrict__ Wv, const float* __restrict__ Wc,
                       const float* __restrict__ Wout,
                       unsigned short* __restrict__ Wtv,    // [512][256]
                       unsigned short* __restrict__ Wout2,  // [256][512]
                       float* __restrict__ stats) {
  int bid = blockIdx.x, j = threadIdx.x;
  if (bid < 256) {
    int i = bid;
    float acc = 0.f;
    for (int c = 0; c < 256; ++c) acc += Wq[c * 256 + i] * Wk[c * 256 + j];
    Wtv[i * 256 + j] = f2bf(acc * 0.0625f);               // M row i (1/sqrt(C) folded)
    Wtv[(256 + i) * 256 + j] = f2bf(Wv[i * 256 + j]);     // Wv row i
  } else if (bid < 512) {
    int o = bid - 256;
    float acc = 0.f;
    for (int c = 0; c < 256; ++c) acc += Wout[o * 256 + c] * Wc[c * 256 + j];
    Wout2[o * 512 + 256 + j] = f2bf(acc);                 // W2 = Wout*Wc
    Wout2[o * 512 + j] = f2bf(Wout[o * 256 + j]);         // Wout
  } else {
    stats[(bid - 512) * 256 + j] = 0.f;                   // zero 4096 partials
  }
}

// ---------------- x (B,C,L) fp32 -> Xt[t][c] bf16 (LDS-tiled 64x64 transpose)
__global__ void k_transpose(const float* __restrict__ x, unsigned short* __restrict__ Xt) {
  __shared__ float tile[64 * 65];
  int bid = blockIdx.x;
  int b = bid >> 8, cb = (bid >> 6) & 3, lb = bid & 63;
  int c0 = cb * 64, l0 = lb * 64, t = threadIdx.x;
#pragma unroll
  for (int i = 0; i < 4; ++i) {
    int idx = i * 256 + t, r = idx >> 4, ch = idx & 15;
    float4 v = *(const float4*)(x + ((size_t)(b * 256 + c0 + r)) * 4096 + l0 + ch * 4);
    tile[r * 65 + ch * 4 + 0] = v.x; tile[r * 65 + ch * 4 + 1] = v.y;
    tile[r * 65 + ch * 4 + 2] = v.z; tile[r * 65 + ch * 4 + 3] = v.w;
  }
  __syncthreads();
#pragma unroll
  for (int i = 0; i < 2; ++i) {
    int idx = i * 256 + t, r = idx >> 3, ch = idx & 7;
    v8u o;
#pragma unroll
    for (int j = 0; j < 8; ++j) o[j] = f2bf(tile[(ch * 8 + j) * 65 + r]);
    *(v8u*)(Xt + ((size_t)(b * 4096 + l0 + r)) * 256 + c0 + ch * 8) = o;
  }
}

// ---------------- fused per-l: T gemm -> S^T -> reg softmax -> VT gemm -> P*V -> virt + GN
// LDS (byte offsets), 81152 total -> 2 blocks/CU:
//   Xs[64][264]@0 (33792)
//   Tb @33792 (36864): holds T[64][264] -> VT[256][72] -> virt[64][264] (sequential reuse)
//   Ps[64][72]@70656 (9216)
//   red f32[64][4]@79872 (cols 0-1: max halves, cols 2-3: sum halves)
//   rowv f32[64]@80896
__global__ __launch_bounds__(512, 4) void k_fused(const unsigned short* __restrict__ Xt,
                                                  const unsigned short* __restrict__ Wtv,
                                                  unsigned short* __restrict__ Virt,
                                                  float* __restrict__ stats) {
  extern __shared__ char smem[];
  unsigned short* Xs  = (unsigned short*)(smem);
  unsigned short* Tb  = (unsigned short*)(smem + 33792);
  unsigned short* Ps  = (unsigned short*)(smem + 70656);
  float*          red = (float*)(smem + 79872);
  float*          rowv= (float*)(smem + 80896);

  int l = blockIdx.x, t = threadIdx.x, lane = t & 63, w = t >> 6;
  int fr = lane & 15, kq = (lane >> 4) * 8, qr = (lane >> 4) * 4;

  // stage X_l: 64 rows (b) x 256 ch
#pragma unroll
  for (int i = 0; i < 4; ++i) {
    int idx = i * 512 + t, r = idx >> 5, ch = idx & 31;
    *(v8u*)(Xs + r * 264 + ch * 8) = *(const v8u*)(Xt + ((size_t)(r * 4096 + l)) * 256 + ch * 8);
  }
  __syncthreads();

  {  // Phase 1: T = Xs * M^T  (64 x 256, K=256); wave w -> cols [w*32, w*32+32)
    int n0 = w * 32;
    f32x4 acc[4][2];
#pragma unroll
    for (int mi = 0; mi < 4; ++mi)
#pragma unroll
      for (int nj = 0; nj < 2; ++nj) acc[mi][nj] = (f32x4){0.f, 0.f, 0.f, 0.f};
#pragma unroll
    for (int kc = 0; kc < 8; ++kc) {
      v8s a[4], b[2];
#pragma unroll
      for (int mi = 0; mi < 4; ++mi) a[mi] = *(const v8s*)(Xs + (mi * 16 + fr) * 264 + kc * 32 + kq);
#pragma unroll
      for (int nj = 0; nj < 2; ++nj)
        b[nj] = *(const v8s*)(Wtv + ((size_t)(n0 + nj * 16 + fr)) * 256 + kc * 32 + kq);
#pragma unroll
      for (int mi = 0; mi < 4; ++mi)
#pragma unroll
        for (int nj = 0; nj < 2; ++nj) acc[mi][nj] = MFMA16(a[mi], b[nj], acc[mi][nj]);
    }
#pragma unroll
    for (int mi = 0; mi < 4; ++mi)
#pragma unroll
      for (int nj = 0; nj < 2; ++nj)
#pragma unroll
        for (int i = 0; i < 4; ++i)
          Tb[(mi * 16 + qr + i) * 264 + n0 + nj * 16 + fr] = f2bf(acc[mi][nj][i]);
  }
  __syncthreads();

  // Phase 2: S^T = Tb * Xs^T ; wave w -> b-tile (w&3), d-tiles {2*(w>>2), 2*(w>>2)+1}.
  // Lane holds S^T[d = (dp+j)*16+qr+i][b = b0+fr] -> softmax over d is per-lane + shfl.
  int b0 = (w & 3) * 16, dp = (w >> 2) * 2, half = w >> 2;
  f32x4 sacc[2];
  sacc[0] = (f32x4){0.f, 0.f, 0.f, 0.f};
  sacc[1] = (f32x4){0.f, 0.f, 0.f, 0.f};
  {
#pragma unroll
    for (int kc = 0; kc < 8; ++kc) {
      v8s bb = *(const v8s*)(Xs + (b0 + fr) * 264 + kc * 32 + kq);
#pragma unroll
      for (int j = 0; j < 2; ++j) {
        v8s a = *(const v8s*)(Tb + ((dp + j) * 16 + fr) * 264 + kc * 32 + kq);
        sacc[j] = MFMA16(a, bb, sacc[j]);
      }
    }
    float pm = -1e30f;
#pragma unroll
    for (int j = 0; j < 2; ++j)
#pragma unroll
      for (int i = 0; i < 4; ++i) pm = fmaxf(pm, sacc[j][i]);
    pm = fmaxf(pm, __shfl_xor(pm, 16));
    pm = fmaxf(pm, __shfl_xor(pm, 32));
    if (lane < 16) red[(b0 + lane) * 4 + half] = pm;
  }
  __syncthreads();

  {  // Phase 3a: finish softmax in registers, write P (bf16) + partial sums
    float m = fmaxf(red[(b0 + fr) * 4 + 0], red[(b0 + fr) * 4 + 1]);
    float ps = 0.f;
#pragma unroll
    for (int j = 0; j < 2; ++j) {
      v4u pk;
#pragma unroll
      for (int i = 0; i < 4; ++i) {
        float e = __expf(sacc[j][i] - m);
        ps += e;
        pk[i] = f2bf(e);
      }
      *(v4u*)(Ps + (b0 + fr) * 72 + (dp + j) * 16 + qr) = pk;
    }
    ps += __shfl_xor(ps, 16);
    ps += __shfl_xor(ps, 32);
    if (lane < 16) red[(b0 + lane) * 4 + 2 + half] = ps;
  }

  {  // Phase 3b: VT = Wv * Xs^T (256 x 64, K=256) -> Tb as VT[c][d] stride 72 (T is dead)
    int c0 = w * 32;
    f32x4 vacc[2][4];
#pragma unroll
    for (int ci = 0; ci < 2; ++ci)
#pragma unroll
      for (int di = 0; di < 4; ++di) vacc[ci][di] = (f32x4){0.f, 0.f, 0.f, 0.f};
#pragma unroll
    for (int kc = 0; kc < 8; ++kc) {
      v8s a[2], b[4];
#pragma unroll
      for (int ci = 0; ci < 2; ++ci)
        a[ci] = *(const v8s*)(Wtv + ((size_t)(256 + c0 + ci * 16 + fr)) * 256 + kc * 32 + kq);
#pragma unroll
      for (int di = 0; di < 4; ++di) b[di] = *(const v8s*)(Xs + (di * 16 + fr) * 264 + kc * 32 + kq);
#pragma unroll
      for (int ci = 0; ci < 2; ++ci)
#pragma unroll
        for (int di = 0; di < 4; ++di) vacc[ci][di] = MFMA16(a[ci], b[di], vacc[ci][di]);
    }
#pragma unroll
    for (int ci = 0; ci < 2; ++ci)
#pragma unroll
      for (int di = 0; di < 4; ++di)
#pragma unroll
        for (int i = 0; i < 4; ++i)
          Tb[(c0 + ci * 16 + qr + i) * 72 + di * 16 + fr] = f2bf(vacc[ci][di][i]);
  }
  __syncthreads();

  if (t < 64) rowv[t] = 1.f / (red[t * 4 + 2] + red[t * 4 + 3]);

  // Phase 4: virt = P * V  (64 x 256, K=64); wave w -> cols [w*32, w*32+32)
  f32x4 pacc[4][2];
#pragma unroll
  for (int mi = 0; mi < 4; ++mi) { pacc[mi][0] = (f32x4){0,0,0,0}; pacc[mi][1] = (f32x4){0,0,0,0}; }
  {
    int n0 = w * 32;
#pragma unroll
    for (int kc = 0; kc < 2; ++kc) {
      v8s a[4], b[2];
#pragma unroll
      for (int mi = 0; mi < 4; ++mi) a[mi] = *(const v8s*)(Ps + (mi * 16 + fr) * 72 + kc * 32 + kq);
#pragma unroll
      for (int nj = 0; nj < 2; ++nj)
        b[nj] = *(const v8s*)(Tb + (n0 + nj * 16 + fr) * 72 + kc * 32 + kq);
#pragma unroll
      for (int mi = 0; mi < 4; ++mi)
#pragma unroll
        for (int nj = 0; nj < 2; ++nj) pacc[mi][nj] = MFMA16(a[mi], b[nj], pacc[mi][nj]);
    }
  }
  __syncthreads();  // all PV reads of VT done; rowv published

  {  // repack scaled virt into Tb rows [64][264]
    int n0 = w * 32;
#pragma unroll
    for (int mi = 0; mi < 4; ++mi)
#pragma unroll
      for (int i = 0; i < 4; ++i) {
        float inv = rowv[mi * 16 + qr + i];
#pragma unroll
        for (int nj = 0; nj < 2; ++nj)
          Tb[(mi * 16 + qr + i) * 264 + n0 + nj * 16 + fr] = f2bf(pacc[mi][nj][i] * inv);
      }
  }
  __syncthreads();

  {  // Phase 5: coalesced virt store + fused GN partial stats
    int r = t >> 3, seg = t & 7;  // 8 threads per row, 32 channels each
    float s = 0.f, s2 = 0.f;
#pragma unroll
    for (int c4 = 0; c4 < 4; ++c4) {
      v8u v = *(const v8u*)(Tb + r * 264 + seg * 32 + c4 * 8);
#pragma unroll
      for (int j = 0; j < 8; ++j) { float f = bf2f(v[j]); s += f; s2 += f * f; }
      *(v8u*)(Virt + ((size_t)(r * 4096 + l)) * 256 + seg * 32 + c4 * 8) = v;
    }
#pragma unroll
    for (int o = 4; o > 0; o >>= 1) { s += __shfl_xor(s, o); s2 += __shfl_xor(s2, o); }
    if (seg == 0) {
      int slot = blockIdx.x & 31;
      atomicAdd(&stats[slot * 128 + r], s);
      atomicAdd(&stats[slot * 128 + 64 + r], s2);
    }
  }
}

__global__ void k_finalize(float* __restrict__ stats) {
  int t = threadIdx.x;
  if (t < 64) {
    float s = 0.f, s2 = 0.f;
    for (int sl = 0; sl < 32; ++sl) { s += stats[sl * 128 + t]; s2 += stats[sl * 128 + 64 + t]; }
    const float inv = 1.f / 1048576.f;  // C*L
    float m = s * inv;
    float var = s2 * inv - m * m;
    stats[4096 + t] = m;
    stats[4160 + t] = rsqrtf(var + 1e-5f);
  }
}

// ---------------- out = [Xt | relu(gn(virt))] * [Wout | W2]^T : K=512, BM=64, BN=256
__global__ void k_gemm_out(const unsigned short* __restrict__ Xt,
                           const unsigned short* __restrict__ Virt,
                           const unsigned short* __restrict__ Wout2,
                           const float* __restrict__ stats,
                           const float* __restrict__ gamma,
                           const float* __restrict__ beta,
                           float* __restrict__ out) {
  __shared__ unsigned short As[64 * 72];
  __shared__ unsigned short Bs[256 * 72];
  int t = threadIdx.x, lane = t & 63, wv = t >> 6;
  size_t t0 = (size_t)blockIdx.x * 64;
  int b = (int)(t0 >> 12);
  float mean = stats[4096 + b], rstd = stats[4160 + b];  // uniform per block (64 | 4096)
  int n0 = wv * 64;
  f32x4 acc[4][4];
#pragma unroll
  for (int mi = 0; mi < 4; ++mi)
#pragma unroll
    for (int ni = 0; ni < 4; ++ni) acc[mi][ni] = (f32x4){0.f, 0.f, 0.f, 0.f};
  for (int kc = 0; kc < 8; ++kc) {
    __syncthreads();
#pragma unroll
    for (int i = 0; i < 2; ++i) {  // stage A (64 x 64)
      int idx = i * 256 + t, r = idx >> 3, ch = idx & 7;
      if (kc < 4) {
        *(v8u*)(As + r * 72 + ch * 8) = *(const v8u*)(Xt + (t0 + r) * 256 + kc * 64 + ch * 8);
      } else {
        v8u v = *(const v8u*)(Virt + (t0 + r) * 256 + (kc - 4) * 64 + ch * 8);
        int cb = (kc - 4) * 64 + ch * 8;
        float4 g0 = *(const float4*)(gamma + cb), g1 = *(const float4*)(gamma + cb + 4);
        float4 bb0 = *(const float4*)(beta + cb), bb1 = *(const float4*)(beta + cb + 4);
        float gs[8] = {g0.x, g0.y, g0.z, g0.w, g1.x, g1.y, g1.z, g1.w};
        float bs[8] = {bb0.x, bb0.y, bb0.z, bb0.w, bb1.x, bb1.y, bb1.z, bb1.w};
        v8u o;
#pragma unroll
        for (int j = 0; j < 8; ++j) {
          float z = (bf2f(v[j]) - mean) * rstd * gs[j] + bs[j];
          o[j] = f2bf(fmaxf(z, 0.f));
        }
        *(v8u*)(As + r * 72 + ch * 8) = o;
      }
    }
#pragma unroll
    for (int i = 0; i < 8; ++i) {  // stage B (256 x 64)
      int idx = i * 256 + t, r = idx >> 3, ch = idx & 7;
      *(v8u*)(Bs + r * 72 + ch * 8) = *(const v8u*)(Wout2 + r * 512 + kc * 64 + ch * 8);
    }
    __syncthreads();
#pragma unroll
    for (int ks = 0; ks < 2; ++ks) {
      int kq = ks * 32 + (lane >> 4) * 8;
      v8s a[4], bb[4];
#pragma unroll
      for (int mi = 0; mi < 4; ++mi) a[mi] = *(const v8s*)(As + (mi * 16 + (lane & 15)) * 72 + kq);
#pragma unroll
      for (int ni = 0; ni < 4; ++ni)
        bb[ni] = *(const v8s*)(Bs + (n0 + ni * 16 + (lane & 15)) * 72 + kq);
#pragma unroll
      for (int mi = 0; mi < 4; ++mi)
#pragma unroll
        for (int ni = 0; ni < 4; ++ni) acc[mi][ni] = MFMA16(a[mi], bb[ni], acc[mi][ni]);
    }
  }
  int qr = (lane >> 4) * 4, lbase = (int)(t0 & 4095);
#pragma unroll
  for (int mi = 0; mi < 4; ++mi)
#pragma unroll
    for (int ni = 0; ni < 4; ++ni)
#pragma unroll
      for (int i = 0; i < 4; ++i) {
        int ll = lbase + mi * 16 + qr + i;
        int o = n0 + ni * 16 + (lane & 15);
        out[((size_t)(b * 256 + o)) * 4096 + ll] = acc[mi][ni][i];
      }
}

extern "C" void kernel_launch(void* const* d_in, const int* in_sizes, int n_in,
                              void* d_out, int out_size, void* d_ws, size_t ws_size,
                              hipStream_t stream) {
  const float* x     = (const float*)d_in[0];
  const float* Wq    = (const float*)d_in[1];
  const float* Wk    = (const float*)d_in[2];
  const float* Wv    = (const float*)d_in[3];
  const float* Wc    = (const float*)d_in[4];
  const float* Wout  = (const float*)d_in[5];
  const float* gamma = (const float*)d_in[6];
  const float* beta  = (const float*)d_in[7];
  float* out = (float*)d_out;
  char* ws = (char*)d_ws;
  unsigned short* Xt   = (unsigned short*)(ws);
  unsigned short* Virt = (unsigned short*)(ws + 134217728ull);
  unsigned short* Wtv  = (unsigned short*)(ws + 268435456ull);
  unsigned short* W2   = (unsigned short*)(ws + 268697600ull);
  float* stats         = (float*)(ws + 268959744ull);

  static const int kFusedLds = 81152;  // 2 blocks/CU (2x81152 = 162304 <= 163840)
  hipFuncSetAttribute((const void*)k_fused, hipFuncAttributeMaxDynamicSharedMemorySize,
                      kFusedLds);  // idempotent host-side call; capture-safe

  k_prep<<<528, 256, 0, stream>>>(Wq, Wk, Wv, Wc, Wout, Wtv, W2, stats);
  k_transpose<<<16384, 256, 0, stream>>>(x, Xt);
  k_fused<<<4096, 512, kFusedLds, stream>>>(Xt, Wtv, Virt, stats);
  k_finalize<<<1, 64, 0, stream>>>(stats);
  k_gemm_out<<<4096, 256, 0, stream>>>(Xt, Virt, W2, stats, gamma, beta, out);
}

// Round 2
// 797.888 us; speedup vs baseline: 1.1330x; 1.0826x over previous
//
#include <hip/hip_runtime.h>

// B=64, C=256, L=4096. Tokens b-major: t = b*4096 + l.
// ws: Xt bf16[262144][256] @0 (128MB); Virt bf16[262144][256] @128MB (128MB);
//     Wtv bf16[512][256] @256MB; Wout2 bf16[256][512]; stats fp32[4224]
//     stats: [32][128] partial (sum,b | sumsq,b) then mean[64]@4096, rstd[64]@4160

typedef __attribute__((ext_vector_type(8))) short          v8s;   // 8 x bf16 bits
typedef __attribute__((ext_vector_type(8))) unsigned short v8u;
typedef __attribute__((ext_vector_type(4))) unsigned short v4u;
typedef __attribute__((ext_vector_type(4))) float          f32x4;

#define MFMA16(a, b, c) __builtin_amdgcn_mfma_f32_16x16x32_bf16((a), (b), (c), 0, 0, 0)

// async global->LDS DMA, 16B per lane; LDS dest = wave-uniform base + lane*16
#define GLOAD16(g, l)                                                            \
  __builtin_amdgcn_global_load_lds(                                              \
      (const __attribute__((address_space(1))) unsigned int*)(const void*)(g),   \
      (__attribute__((address_space(3))) unsigned int*)(void*)(l), 16, 0, 0)

static __device__ __forceinline__ unsigned short f2bf(float f) {
  union { float f; unsigned u; } v; v.f = f;
  unsigned r = (v.u + 0x7FFFu + ((v.u >> 16) & 1u)) >> 16;  // RNE
  return (unsigned short)r;
}
static __device__ __forceinline__ float bf2f(unsigned short h) {
  union { unsigned u; float f; } v; v.u = ((unsigned)h) << 16; return v.f;
}

// ---------------- prep: M = Wq^T Wk / 16, W2 = Wout*Wc, bf16 packs, zero stats
__global__ void k_prep(const float* __restrict__ Wq, const float* __restrict__ Wk,
                       const float* __restrict__ Wv, const float* __restrict__ Wc,
                       const float* __restrict__ Wout,
                       unsigned short* __restrict__ Wtv,    // [512][256]
                       unsigned short* __restrict__ Wout2,  // [256][512]
                       float* __restrict__ stats) {
  int bid = blockIdx.x, j = threadIdx.x;
  if (bid < 256) {
    int i = bid;
    float acc = 0.f;
    for (int c = 0; c < 256; ++c) acc += Wq[c * 256 + i] * Wk[c * 256 + j];
    Wtv[i * 256 + j] = f2bf(acc * 0.0625f);               // M row i (1/sqrt(C) folded)
    Wtv[(256 + i) * 256 + j] = f2bf(Wv[i * 256 + j]);     // Wv row i
  } else if (bid < 512) {
    int o = bid - 256;
    float acc = 0.f;
    for (int c = 0; c < 256; ++c) acc += Wout[o * 256 + c] * Wc[c * 256 + j];
    Wout2[o * 512 + 256 + j] = f2bf(acc);                 // W2 = Wout*Wc
    Wout2[o * 512 + j] = f2bf(Wout[o * 256 + j]);         // Wout
  } else {
    stats[(bid - 512) * 256 + j] = 0.f;                   // zero 4096 partials
  }
}

// ---------------- x (B,C,L) fp32 -> Xt[t][c] bf16 (LDS-tiled 64x64 transpose)
__global__ void k_transpose(const float* __restrict__ x, unsigned short* __restrict__ Xt) {
  __shared__ float tile[64 * 65];
  int bid = blockIdx.x;
  int b = bid >> 8, cb = (bid >> 6) & 3, lb = bid & 63;
  int c0 = cb * 64, l0 = lb * 64, t = threadIdx.x;
#pragma unroll
  for (int i = 0; i < 4; ++i) {
    int idx = i * 256 + t, r = idx >> 4, ch = idx & 15;
    float4 v = *(const float4*)(x + ((size_t)(b * 256 + c0 + r)) * 4096 + l0 + ch * 4);
    tile[r * 65 + ch * 4 + 0] = v.x; tile[r * 65 + ch * 4 + 1] = v.y;
    tile[r * 65 + ch * 4 + 2] = v.z; tile[r * 65 + ch * 4 + 3] = v.w;
  }
  __syncthreads();
#pragma unroll
  for (int i = 0; i < 2; ++i) {
    int idx = i * 256 + t, r = idx >> 3, ch = idx & 7;
    v8u o;
#pragma unroll
    for (int j = 0; j < 8; ++j) o[j] = f2bf(tile[(ch * 8 + j) * 65 + r]);
    *(v8u*)(Xt + ((size_t)(b * 4096 + l0 + r)) * 256 + c0 + ch * 8) = o;
  }
}

// ---------------- fused per-l: T gemm -> S^T -> reg softmax -> VT gemm -> P*V -> virt + GN
// LDS (byte offsets), 81152 total -> 2 blocks/CU:
//   Xs[64][264]@0 (33792)
//   Tb @33792 (36864): holds T[64][264] -> VT[256][72] -> virt[64][264] (sequential reuse)
//   Ps[64][72]@70656 (9216)
//   red f32[64][4]@79872 (cols 0-1: max halves, cols 2-3: sum halves)
//   rowv f32[64]@80896
__global__ __launch_bounds__(512, 4) void k_fused(const unsigned short* __restrict__ Xt,
                                                  const unsigned short* __restrict__ Wtv,
                                                  unsigned short* __restrict__ Virt,
                                                  float* __restrict__ stats) {
  extern __shared__ char smem[];
  unsigned short* Xs  = (unsigned short*)(smem);
  unsigned short* Tb  = (unsigned short*)(smem + 33792);
  unsigned short* Ps  = (unsigned short*)(smem + 70656);
  float*          red = (float*)(smem + 79872);
  float*          rowv= (float*)(smem + 80896);

  int l = blockIdx.x, t = threadIdx.x, lane = t & 63, w = t >> 6;
  int fr = lane & 15, kq = (lane >> 4) * 8, qr = (lane >> 4) * 4;

  // stage X_l: 64 rows (b) x 256 ch
#pragma unroll
  for (int i = 0; i < 4; ++i) {
    int idx = i * 512 + t, r = idx >> 5, ch = idx & 31;
    *(v8u*)(Xs + r * 264 + ch * 8) = *(const v8u*)(Xt + ((size_t)(r * 4096 + l)) * 256 + ch * 8);
  }
  __syncthreads();

  {  // Phase 1: T = Xs * M^T  (64 x 256, K=256); wave w -> cols [w*32, w*32+32)
    int n0 = w * 32;
    f32x4 acc[4][2];
#pragma unroll
    for (int mi = 0; mi < 4; ++mi)
#pragma unroll
      for (int nj = 0; nj < 2; ++nj) acc[mi][nj] = (f32x4){0.f, 0.f, 0.f, 0.f};
#pragma unroll
    for (int kc = 0; kc < 8; ++kc) {
      v8s a[4], b[2];
#pragma unroll
      for (int mi = 0; mi < 4; ++mi) a[mi] = *(const v8s*)(Xs + (mi * 16 + fr) * 264 + kc * 32 + kq);
#pragma unroll
      for (int nj = 0; nj < 2; ++nj)
        b[nj] = *(const v8s*)(Wtv + ((size_t)(n0 + nj * 16 + fr)) * 256 + kc * 32 + kq);
#pragma unroll
      for (int mi = 0; mi < 4; ++mi)
#pragma unroll
        for (int nj = 0; nj < 2; ++nj) acc[mi][nj] = MFMA16(a[mi], b[nj], acc[mi][nj]);
    }
#pragma unroll
    for (int mi = 0; mi < 4; ++mi)
#pragma unroll
      for (int nj = 0; nj < 2; ++nj)
#pragma unroll
        for (int i = 0; i < 4; ++i)
          Tb[(mi * 16 + qr + i) * 264 + n0 + nj * 16 + fr] = f2bf(acc[mi][nj][i]);
  }
  __syncthreads();

  // Phase 2: S^T = Tb * Xs^T ; wave w -> b-tile (w&3), d-tiles {2*(w>>2), 2*(w>>2)+1}.
  // Lane holds S^T[d = (dp+j)*16+qr+i][b = b0+fr] -> softmax over d is per-lane + shfl.
  int b0 = (w & 3) * 16, dp = (w >> 2) * 2, half = w >> 2;
  f32x4 sacc[2];
  sacc[0] = (f32x4){0.f, 0.f, 0.f, 0.f};
  sacc[1] = (f32x4){0.f, 0.f, 0.f, 0.f};
  {
#pragma unroll
    for (int kc = 0; kc < 8; ++kc) {
      v8s bb = *(const v8s*)(Xs + (b0 + fr) * 264 + kc * 32 + kq);
#pragma unroll
      for (int j = 0; j < 2; ++j) {
        v8s a = *(const v8s*)(Tb + ((dp + j) * 16 + fr) * 264 + kc * 32 + kq);
        sacc[j] = MFMA16(a, bb, sacc[j]);
      }
    }
    float pm = -1e30f;
#pragma unroll
    for (int j = 0; j < 2; ++j)
#pragma unroll
      for (int i = 0; i < 4; ++i) pm = fmaxf(pm, sacc[j][i]);
    pm = fmaxf(pm, __shfl_xor(pm, 16));
    pm = fmaxf(pm, __shfl_xor(pm, 32));
    if (lane < 16) red[(b0 + lane) * 4 + half] = pm;
  }
  __syncthreads();

  {  // Phase 3a: finish softmax in registers, write P (bf16) + partial sums
    float m = fmaxf(red[(b0 + fr) * 4 + 0], red[(b0 + fr) * 4 + 1]);
    float ps = 0.f;
#pragma unroll
    for (int j = 0; j < 2; ++j) {
      v4u pk;
#pragma unroll
      for (int i = 0; i < 4; ++i) {
        float e = __expf(sacc[j][i] - m);
        ps += e;
        pk[i] = f2bf(e);
      }
      *(v4u*)(Ps + (b0 + fr) * 72 + (dp + j) * 16 + qr) = pk;
    }
    ps += __shfl_xor(ps, 16);
    ps += __shfl_xor(ps, 32);
    if (lane < 16) red[(b0 + lane) * 4 + 2 + half] = ps;
  }

  {  // Phase 3b: VT = Wv * Xs^T (256 x 64, K=256) -> Tb as VT[c][d] stride 72 (T is dead)
    int c0 = w * 32;
    f32x4 vacc[2][4];
#pragma unroll
    for (int ci = 0; ci < 2; ++ci)
#pragma unroll
      for (int di = 0; di < 4; ++di) vacc[ci][di] = (f32x4){0.f, 0.f, 0.f, 0.f};
#pragma unroll
    for (int kc = 0; kc < 8; ++kc) {
      v8s a[2], b[4];
#pragma unroll
      for (int ci = 0; ci < 2; ++ci)
        a[ci] = *(const v8s*)(Wtv + ((size_t)(256 + c0 + ci * 16 + fr)) * 256 + kc * 32 + kq);
#pragma unroll
      for (int di = 0; di < 4; ++di) b[di] = *(const v8s*)(Xs + (di * 16 + fr) * 264 + kc * 32 + kq);
#pragma unroll
      for (int ci = 0; ci < 2; ++ci)
#pragma unroll
        for (int di = 0; di < 4; ++di) vacc[ci][di] = MFMA16(a[ci], b[di], vacc[ci][di]);
    }
#pragma unroll
    for (int ci = 0; ci < 2; ++ci)
#pragma unroll
      for (int di = 0; di < 4; ++di)
#pragma unroll
        for (int i = 0; i < 4; ++i)
          Tb[(c0 + ci * 16 + qr + i) * 72 + di * 16 + fr] = f2bf(vacc[ci][di][i]);
  }
  __syncthreads();

  if (t < 64) rowv[t] = 1.f / (red[t * 4 + 2] + red[t * 4 + 3]);

  // Phase 4: virt = P * V  (64 x 256, K=64); wave w -> cols [w*32, w*32+32)
  f32x4 pacc[4][2];
#pragma unroll
  for (int mi = 0; mi < 4; ++mi) { pacc[mi][0] = (f32x4){0,0,0,0}; pacc[mi][1] = (f32x4){0,0,0,0}; }
  {
    int n0 = w * 32;
#pragma unroll
    for (int kc = 0; kc < 2; ++kc) {
      v8s a[4], b[2];
#pragma unroll
      for (int mi = 0; mi < 4; ++mi) a[mi] = *(const v8s*)(Ps + (mi * 16 + fr) * 72 + kc * 32 + kq);
#pragma unroll
      for (int nj = 0; nj < 2; ++nj)
        b[nj] = *(const v8s*)(Tb + (n0 + nj * 16 + fr) * 72 + kc * 32 + kq);
#pragma unroll
      for (int mi = 0; mi < 4; ++mi)
#pragma unroll
        for (int nj = 0; nj < 2; ++nj) pacc[mi][nj] = MFMA16(a[mi], b[nj], pacc[mi][nj]);
    }
  }
  __syncthreads();  // all PV reads of VT done; rowv published

  {  // repack scaled virt into Tb rows [64][264]
    int n0 = w * 32;
#pragma unroll
    for (int mi = 0; mi < 4; ++mi)
#pragma unroll
      for (int i = 0; i < 4; ++i) {
        float inv = rowv[mi * 16 + qr + i];
#pragma unroll
        for (int nj = 0; nj < 2; ++nj)
          Tb[(mi * 16 + qr + i) * 264 + n0 + nj * 16 + fr] = f2bf(pacc[mi][nj][i] * inv);
      }
  }
  __syncthreads();

  {  // Phase 5: coalesced virt store + fused GN partial stats
    int r = t >> 3, seg = t & 7;  // 8 threads per row, 32 channels each
    float s = 0.f, s2 = 0.f;
#pragma unroll
    for (int c4 = 0; c4 < 4; ++c4) {
      v8u v = *(const v8u*)(Tb + r * 264 + seg * 32 + c4 * 8);
#pragma unroll
      for (int j = 0; j < 8; ++j) { float f = bf2f(v[j]); s += f; s2 += f * f; }
      *(v8u*)(Virt + ((size_t)(r * 4096 + l)) * 256 + seg * 32 + c4 * 8) = v;
    }
#pragma unroll
    for (int o = 4; o > 0; o >>= 1) { s += __shfl_xor(s, o); s2 += __shfl_xor(s2, o); }
    if (seg == 0) {
      int slot = blockIdx.x & 31;
      atomicAdd(&stats[slot * 128 + r], s);
      atomicAdd(&stats[slot * 128 + 64 + r], s2);
    }
  }
}

__global__ void k_finalize(float* __restrict__ stats) {
  int t = threadIdx.x;
  if (t < 64) {
    float s = 0.f, s2 = 0.f;
    for (int sl = 0; sl < 32; ++sl) { s += stats[sl * 128 + t]; s2 += stats[sl * 128 + 64 + t]; }
    const float inv = 1.f / 1048576.f;  // C*L
    float m = s * inv;
    float var = s2 * inv - m * m;
    stats[4096 + t] = m;
    stats[4160 + t] = rsqrtf(var + 1e-5f);
  }
}

// ---------------- out = [Xt | relu(gn(virt))] * [Wout | W2]^T : K=512, BM=256, BN=256
// 2-phase double-buffered global_load_lds pipeline; XOR-swizzled tiles (m173 both-sides).
// LDS: buf0 @0: A[256][64ch] (32KB linear rows of 128B) + B[256][64ch] @32768; buf1 @65536.
// Swizzle: lds_byte(r, kb) = r*128 + (kb ^ ((r&7)<<4)); gload dest linear, global src
// pre-swizzled (slot s_phys fetches logical slot s_phys ^ (r&7)).
__global__ __launch_bounds__(512, 2) void k_gemm_out(const unsigned short* __restrict__ Xt,
                                                     const unsigned short* __restrict__ Virt,
                                                     const unsigned short* __restrict__ Wout2,
                                                     const float* __restrict__ stats,
                                                     const float* __restrict__ gamma,
                                                     const float* __restrict__ beta,
                                                     float* __restrict__ out) {
  extern __shared__ char smem[];
  int t = threadIdx.x, lane = t & 63, w = t >> 6;
  int fr = lane & 15;
  int wm = w >> 2, wn = w & 3;  // 2M x 4N wave grid; wave tile 128x64
  size_t t0 = (size_t)blockIdx.x * 256;
  int b = (int)(t0 >> 12);
  float mean = stats[4096 + b], rstd = stats[4160 + b];  // uniform per block (256 | 4096)

  f32x4 acc[8][4];
#pragma unroll
  for (int mi = 0; mi < 8; ++mi)
#pragma unroll
    for (int ni = 0; ni < 4; ++ni) acc[mi][ni] = (f32x4){0.f, 0.f, 0.f, 0.f};

  // per-lane staging coordinates (waves 0-3 stage A rows, waves 4-7 stage B rows)
  int srow = (lane >> 3);         // row within 8-row group
  int sph = lane & 7;             // physical 16B slot

#define STAGE_TILE(BUF, KC)                                                          \
  do {                                                                               \
    char* base_ = smem + (BUF) * 65536;                                              \
    if (w < 4) {                                                                     \
      const unsigned short* s0_ =                                                    \
          ((KC) < 4) ? (Xt + (KC) * 64) : (Virt + ((KC) - 4) * 64);                  \
      _Pragma("unroll") for (int g_ = 0; g_ < 8; ++g_) {                             \
        int r_ = w * 64 + g_ * 8 + srow;                                             \
        int sl_ = sph ^ (r_ & 7);                                                    \
        GLOAD16(s0_ + (t0 + r_) * 256 + sl_ * 8, base_ + w * 8192 + g_ * 1024);      \
      }                                                                              \
    } else {                                                                         \
      int wb_ = w - 4;                                                               \
      _Pragma("unroll") for (int g_ = 0; g_ < 8; ++g_) {                             \
        int r_ = wb_ * 64 + g_ * 8 + srow;                                           \
        int sl_ = sph ^ (r_ & 7);                                                    \
        GLOAD16(Wout2 + r_ * 512 + (KC) * 64 + sl_ * 8,                              \
                base_ + 32768 + wb_ * 8192 + g_ * 1024);                             \
      }                                                                              \
    }                                                                                \
  } while (0)

  STAGE_TILE(0, 0);
  __syncthreads();

  for (int kc = 0; kc < 8; ++kc) {
    int cur = kc & 1;
    if (kc < 7) STAGE_TILE(cur ^ 1, kc + 1);

    {  // MFMA phase on buf[cur]
      const char* Ab = smem + cur * 65536;
      const char* Bb = Ab + 32768;
#pragma unroll
      for (int ks = 0; ks < 2; ++ks) {
        int xr = (ks * 64 + (lane >> 4) * 16) ^ ((fr & 7) << 4);
        v8s a[8], bb[4];
#pragma unroll
        for (int mi = 0; mi < 8; ++mi)
          a[mi] = *(const v8s*)(Ab + (wm * 128 + mi * 16 + fr) * 128 + xr);
#pragma unroll
        for (int ni = 0; ni < 4; ++ni)
          bb[ni] = *(const v8s*)(Bb + (wn * 64 + ni * 16 + fr) * 128 + xr);
#pragma unroll
        for (int mi = 0; mi < 8; ++mi)
#pragma unroll
          for (int ni = 0; ni < 4; ++ni) acc[mi][ni] = MFMA16(a[mi], bb[ni], acc[mi][ni]);
      }
    }
    __syncthreads();  // drains gload_lds (vmcnt) + ds reads; buf[cur^1] now resident

    if (kc < 7 && kc >= 3) {  // GN+ReLU transform of the just-staged Virt tile (kc+1 >= 4)
      char* Ab = smem + (cur ^ 1) * 65536;
      int s_log = sph ^ ((t >> 3) & 7);  // constant across j (row&7 invariant)
      int cb = (kc + 1 - 4) * 64 + s_log * 8;
      float4 g0 = *(const float4*)(gamma + cb), g1 = *(const float4*)(gamma + cb + 4);
      float4 b0 = *(const float4*)(beta + cb), b1 = *(const float4*)(beta + cb + 4);
      float rg[8] = {g0.x * rstd, g0.y * rstd, g0.z * rstd, g0.w * rstd,
                     g1.x * rstd, g1.y * rstd, g1.z * rstd, g1.w * rstd};
      float sh[8] = {b0.x - mean * rg[0], b0.y - mean * rg[1], b0.z - mean * rg[2],
                     b0.w - mean * rg[3], b1.x - mean * rg[4], b1.y - mean * rg[5],
                     b1.z - mean * rg[6], b1.w - mean * rg[7]};
#pragma unroll
      for (int j = 0; j < 4; ++j) {
        int r = j * 64 + (t >> 3);
        v8u* p = (v8u*)(Ab + r * 128 + sph * 16);
        v8u v = *p, o;
#pragma unroll
        for (int e = 0; e < 8; ++e) {
          float z = fmaf(bf2f(v[e]), rg[e], sh[e]);
          o[e] = f2bf(fmaxf(z, 0.f));
        }
        *p = o;
      }
      __syncthreads();
    }
  }
#undef STAGE_TILE

  // epilogue: C[token = wm*128+mi*16+qr+i][outch = wn*64+ni*16+fr]
  int qr = (lane >> 4) * 4, lbase = (int)(t0 & 4095);
#pragma unroll
  for (int mi = 0; mi < 8; ++mi)
#pragma unroll
    for (int ni = 0; ni < 4; ++ni)
#pragma unroll
      for (int i = 0; i < 4; ++i) {
        int ll = lbase + wm * 128 + mi * 16 + qr + i;
        int o = wn * 64 + ni * 16 + fr;
        out[((size_t)(b * 256 + o)) * 4096 + ll] = acc[mi][ni][i];
      }
}

extern "C" void kernel_launch(void* const* d_in, const int* in_sizes, int n_in,
                              void* d_out, int out_size, void* d_ws, size_t ws_size,
                              hipStream_t stream) {
  const float* x     = (const float*)d_in[0];
  const float* Wq    = (const float*)d_in[1];
  const float* Wk    = (const float*)d_in[2];
  const float* Wv    = (const float*)d_in[3];
  const float* Wc    = (const float*)d_in[4];
  const float* Wout  = (const float*)d_in[5];
  const float* gamma = (const float*)d_in[6];
  const float* beta  = (const float*)d_in[7];
  float* out = (float*)d_out;
  char* ws = (char*)d_ws;
  unsigned short* Xt   = (unsigned short*)(ws);
  unsigned short* Virt = (unsigned short*)(ws + 134217728ull);
  unsigned short* Wtv  = (unsigned short*)(ws + 268435456ull);
  unsigned short* W2   = (unsigned short*)(ws + 268697600ull);
  float* stats         = (float*)(ws + 268959744ull);

  static const int kFusedLds = 81152;   // 2 blocks/CU (2x81152 = 162304 <= 163840)
  static const int kGemmLds  = 131072;  // 2 x (32KB A + 32KB B) double buffer
  hipFuncSetAttribute((const void*)k_fused, hipFuncAttributeMaxDynamicSharedMemorySize,
                      kFusedLds);  // idempotent host-side call; capture-safe
  hipFuncSetAttribute((const void*)k_gemm_out, hipFuncAttributeMaxDynamicSharedMemorySize,
                      kGemmLds);

  k_prep<<<528, 256, 0, stream>>>(Wq, Wk, Wv, Wc, Wout, Wtv, W2, stats);
  k_transpose<<<16384, 256, 0, stream>>>(x, Xt);
  k_fused<<<4096, 512, kFusedLds, stream>>>(Xt, Wtv, Virt, stats);
  k_finalize<<<1, 64, 0, stream>>>(stats);
  k_gemm_out<<<1024, 512, kGemmLds, stream>>>(Xt, Virt, W2, stats, gamma, beta, out);
}